// Round 12
// baseline (461.255 us; speedup 1.0000x reference)
//
#include <hip/hip_runtime.h>

// LSTM: B=512, T=512, I=128, H=50, O=10, fp32.
// R16: lstm_rec — all-f32 datapath (the "fdot2" was scalarized all along).
//  Evidence: instruction-count model with ~5 VALU/half2-dot fits BOTH
//  R9 (560 instr = 1120cyc issue ~= 1125cyc step, pure issue-bound — why
//  every latency fix R5-R13 failed) AND R14/15 (185 instr -> predicted
//  VALUBusy 69%, measured 68%). Real v_dot2 fits neither.
//  Changes:
//   - W_hh stored f32 [gp][56] (prep); h published f32. Dot = 56 v_fma_f32
//     = 112 cyc/wave guaranteed, zero converts.
//   - xp chunk-staged to LDS (64 steps, 25.6KB x2 dbuf): HBM latency paid
//     once per chunk (~14cyc/step amortized); per-step xp = 1 ds_read_u16
//     (imm offset). No global loads in the loop -> __syncthreads drains
//     nothing.
//   - Same 4-wave gate-per-lane structure (R14), double-buffered h, one
//     barrier/step, unroll 4 keeps parity/offsets static (rule #20).
//  xproj (80us, R11-measured) / fc untouched; prep: whh f16 -> f32.

#define BB 512
#define TT 512
#define II 128
#define HH 50
#define GG 200   // 4*H

typedef _Float16 half8v __attribute__((ext_vector_type(8)));
typedef float float4v __attribute__((ext_vector_type(4)));

__device__ __forceinline__ float fsig(float x) {
    return 1.f / (1.f + __expf(-x));
}
__device__ __forceinline__ float ftanh(float x) {
    return 2.f * fsig(2.f * x) - 1.f;
}

// ---------------- Kernel 0: prep (once per launch) ----------------
// Gate permutation: gp = unit*4 + gate  <->  orig g = gate*50 + unit.
// wfrags: W_ih rows in PERMUTED order as f16 MFMA B-fragments
// whh32:  W_hh rows in PERMUTED gp order, padded to 56 f32  [gp 200][56]
// biasv:  b_ih + b_hh in PERMUTED order                     [gp 200]
__global__ __launch_bounds__(256) void prep_kernel(
    const float* __restrict__ W_ih, const float* __restrict__ W_hh,
    const float* __restrict__ b_ih, const float* __restrict__ b_hh,
    _Float16* __restrict__ wfrags, float* __restrict__ whh32,
    float* __restrict__ biasv)
{
    int idx = blockIdx.x * 256 + threadIdx.x;
    if (idx < 3328) {                       // 13*4*64 fragment slots
        int lane = idx & 63, kc = (idx >> 6) & 3, nt = idx >> 8;
        int gp = nt * 16 + (lane & 15);     // permuted gate index
        int k0 = kc * 32 + ((lane >> 4) & 3) * 8;
        half8v v;
        if (gp < GG) {
            int u = gp >> 2, j = gp & 3;
            const float* wr = W_ih + (size_t)(j * HH + u) * II + k0;
            #pragma unroll
            for (int q = 0; q < 8; ++q) v[q] = (_Float16)wr[q];
        } else {
            #pragma unroll
            for (int q = 0; q < 8; ++q) v[q] = (_Float16)0.f;
        }
        *(half8v*)(wfrags + (size_t)idx * 8) = v;
    } else if (idx < 3328 + 2800) {         // 200 gp-rows * 14 quads, f32
        int r = idx - 3328;
        int gp = r / 14, j4 = r % 14;
        int u = gp >> 2, gate = gp & 3;
        #pragma unroll
        for (int j = 0; j < 4; ++j) {
            int hidx = j4 * 4 + j;
            whh32[gp * 56 + hidx] =
                (hidx < HH) ? W_hh[(size_t)(gate * HH + u) * HH + hidx] : 0.f;
        }
    } else if (idx < 3328 + 2800 + GG) {
        int gp = idx - 6128;
        int u = gp >> 2, j = gp & 3;
        biasv[gp] = b_ih[j * HH + u] + b_hh[j * HH + u];
    }
}

// ---------------- Kernel 1: xproj via MFMA, batch-per-block ----------------
__global__ __launch_bounds__(256) void xproj_mfma(
    const float* __restrict__ x, const _Float16* __restrict__ wfrags,
    const float* __restrict__ biasv, _Float16* __restrict__ xp16,
    int t0, int ntile)
{
    __shared__ __align__(16) _Float16 wflds[3328 * 8];   // 53248 B
    __shared__ __align__(16) _Float16 dtile[64 * GG];    // 25600 B
    __shared__ float blds[GG];                           // 800 B
    const int tid = threadIdx.x;
    const int b = blockIdx.x;
    const int w = tid >> 6, l = tid & 63;

    for (int s = tid; s < 3328; s += 256)
        *(float4v*)(wflds + (size_t)s * 8) = *(const float4v*)(wfrags + (size_t)s * 8);
    for (int s = tid; s < GG; s += 256) blds[s] = biasv[s];

    const int row = w * 16 + (l & 15);
    const int kq = (l >> 4) & 3;
    const float* xbase = x + ((size_t)b * TT + (size_t)t0 + row) * II + kq * 8;

    float4 f0[4], f1[4];
    #pragma unroll
    for (int kc = 0; kc < 4; ++kc) {
        f0[kc] = *(const float4*)(xbase + kc * 32);
        f1[kc] = *(const float4*)(xbase + kc * 32 + 4);
    }
    __syncthreads();   // wflds/blds ready

    const int colb = l & 15, rq = l >> 4;

    for (int tt = 0; tt < ntile; ++tt) {
        half8v a[4];
        #pragma unroll
        for (int kc = 0; kc < 4; ++kc) {
            a[kc][0] = (_Float16)f0[kc].x; a[kc][1] = (_Float16)f0[kc].y;
            a[kc][2] = (_Float16)f0[kc].z; a[kc][3] = (_Float16)f0[kc].w;
            a[kc][4] = (_Float16)f1[kc].x; a[kc][5] = (_Float16)f1[kc].y;
            a[kc][6] = (_Float16)f1[kc].z; a[kc][7] = (_Float16)f1[kc].w;
        }
        if (tt + 1 < ntile) {
            const float* xn = xbase + (size_t)(tt + 1) * 64 * II;
            #pragma unroll
            for (int kc = 0; kc < 4; ++kc) {
                f0[kc] = *(const float4*)(xn + kc * 32);
                f1[kc] = *(const float4*)(xn + kc * 32 + 4);
            }
        }

        float4v acc[13];
        #pragma unroll
        for (int nt = 0; nt < 13; ++nt) acc[nt] = (float4v){0.f, 0.f, 0.f, 0.f};
        #pragma unroll
        for (int kc = 0; kc < 4; ++kc) {
            #pragma unroll
            for (int nt = 0; nt < 13; ++nt) {
                half8v bf = *(const half8v*)(wflds + (size_t)(((nt * 4 + kc) * 64) + l) * 8);
                acc[nt] = __builtin_amdgcn_mfma_f32_16x16x32_f16(a[kc], bf, acc[nt], 0, 0, 0);
            }
        }

        __syncthreads();
        #pragma unroll
        for (int nt = 0; nt < 13; ++nt) {
            int g = nt * 16 + colb;
            if (g < GG) {
                float bs = blds[g];
                #pragma unroll
                for (int reg = 0; reg < 4; ++reg)
                    dtile[(w * 16 + rq * 4 + reg) * GG + g] = (_Float16)(acc[nt][reg] + bs);
            }
        }
        __syncthreads();

        _Float16* outp = xp16 + ((size_t)b * ntile + tt) * 64 * GG;
        #pragma unroll
        for (int it = 0; it < 7; ++it) {
            int idx = it * 256 + tid;
            if (idx < 1600) {
                float4v v = *(const float4v*)(dtile + (size_t)idx * 8);
                *(float4v*)(outp + (size_t)idx * 8) = v;
            }
        }
    }
}

// ---------------- Kernel 2: recurrence (gate-per-lane, f32, LDS xp) --------
__global__
__attribute__((amdgpu_flat_work_group_size(256, 256)))
__attribute__((amdgpu_waves_per_eu(1, 2)))
void lstm_rec(
    const _Float16* __restrict__ xp16, const float* __restrict__ whh32,
    float* __restrict__ hs, float* __restrict__ cs, int Tc, int first)
{
    __shared__ __align__(16) _Float16 xbuf[2][64 * GG];  // 51200 B
    __shared__ __align__(16) float hbuf[2][56];          // 448 B
    const int b = blockIdx.x;
    const int tid = threadIdx.x;
    const int gp = (tid < GG) ? tid : 197;   // pads mirror gp=197, never write
    const int u = gp >> 2;
    const int gate = gp & 3;

    // Per-lane weight row (f32, permuted): 14 x float4 = 56 VGPRs, one-time.
    float4v wv[14];
    #pragma unroll
    for (int j = 0; j < 14; ++j)
        wv[j] = *(const float4v*)(whh32 + (size_t)gp * 56 + j * 4);

    float c = (!first) ? cs[b * HH + u] : 0.f;

    const _Float16* xpb0 = xp16 + (size_t)b * Tc * GG;
    const int nchk = Tc >> 6;

    // Prologue: stage chunk 0 + h init.
    #pragma unroll
    for (int it = 0; it < 7; ++it) {
        int s = it * 256 + tid;
        if (s < 1600)
            *(float4v*)(&xbuf[0][0] + (size_t)s * 8) =
                *(const float4v*)(xpb0 + (size_t)s * 8);
    }
    if (tid < 56) {
        hbuf[0][tid] = (tid < HH && !first) ? hs[b * HH + tid] : 0.f;
        hbuf[1][tid] = 0.f;      // pads of both parities stay zero forever
    }
    __syncthreads();

    float hlast = 0.f;
    for (int ch = 0; ch < nchk; ++ch) {
        // Stage next chunk into the other buffer (vmcnt wait paid here,
        // once per 64 steps; ds_writes become visible via step barriers).
        if (ch + 1 < nchk) {
            const _Float16* src = xpb0 + (size_t)(ch + 1) * 64 * GG;
            _Float16* dst = &xbuf[(ch + 1) & 1][0];
            #pragma unroll
            for (int it = 0; it < 7; ++it) {
                int s = it * 256 + tid;
                if (s < 1600)
                    *(float4v*)(dst + (size_t)s * 8) =
                        *(const float4v*)(src + (size_t)s * 8);
            }
        }
        const _Float16* xc = &xbuf[ch & 1][0];

        #pragma unroll 4
        for (int tt = 0; tt < 64; ++tt) {
            const int p = tt & 1;            // static after unroll (64 even
                                             // -> parity continuous across chunks)
            // h broadcast read: 14 b128, uniform addr = LDS broadcast.
            float4v hv[14];
            #pragma unroll
            for (int j = 0; j < 14; ++j)
                hv[j] = *(const float4v*)(&hbuf[p][0] + j * 4);

            float xpf = (float)xc[tt * GG + gp];   // ds_read_u16, imm offset

            // 56 f32 FMA, 4-way split accumulators (14-deep chains).
            float a0 = 0.f, a1 = 0.f, a2 = 0.f, a3 = 0.f;
            #pragma unroll
            for (int j = 0; j < 14; ++j) {
                a0 = fmaf(hv[j][0], wv[j][0], a0);
                a1 = fmaf(hv[j][1], wv[j][1], a1);
                a2 = fmaf(hv[j][2], wv[j][2], a2);
                a3 = fmaf(hv[j][3], wv[j][3], a3);
            }
            float acc = ((a0 + a1) + (a2 + a3)) + xpf;

            // sigmoid for i,f,o; tanh for g, branchless.
            bool isg = (gate == 2);
            float xin = isg ? 2.f * acc : acc;
            float sg = fsig(xin);
            float act = isg ? (2.f * sg - 1.f) : sg;

            // Quad broadcast: lanes u*4..u*4+3 hold (i,f,g,o) of unit u.
            int ai = __builtin_bit_cast(int, act);
            float gi = __builtin_bit_cast(float, __builtin_amdgcn_mov_dpp(ai, 0x00, 0xF, 0xF, true));
            float gf = __builtin_bit_cast(float, __builtin_amdgcn_mov_dpp(ai, 0x55, 0xF, 0xF, true));
            float gg = __builtin_bit_cast(float, __builtin_amdgcn_mov_dpp(ai, 0xAA, 0xF, 0xF, true));
            float go = __builtin_bit_cast(float, __builtin_amdgcn_mov_dpp(ai, 0xFF, 0xF, 0xF, true));

            c = gf * c + gi * gg;            // quad-redundant, consistent
            float hn = go * ftanh(c);

            // Leader writes NEXT parity buffer; one barrier/step (double
            // buffer makes it provably race-free). Nothing global in flight.
            if (tid < GG && gate == 0) hbuf[p ^ 1][u] = hn;
            __syncthreads();

            hlast = hn;
        }
    }

    if (tid < GG && gate == 0) {
        hs[b * HH + u] = hlast;
        cs[b * HH + u] = c;
    }
}

// ---------------- Kernel 3: FC epilogue ----------------
__global__ __launch_bounds__(256) void fc_kernel(
    const float* __restrict__ hs, const float* __restrict__ W_fc,
    const float* __restrict__ b_fc, float* __restrict__ out)
{
    int idx = blockIdx.x * blockDim.x + threadIdx.x;   // 512*10
    if (idx < BB * 10) {
        int b = idx / 10, o = idx % 10;
        float a = b_fc[o];
        #pragma unroll
        for (int kx = 0; kx < HH; ++kx)
            a += hs[b * HH + kx] * W_fc[o * HH + kx];
        out[idx] = a;
    }
}

extern "C" void kernel_launch(void* const* d_in, const int* in_sizes, int n_in,
                              void* d_out, int out_size, void* d_ws, size_t ws_size,
                              hipStream_t stream)
{
    const float* x    = (const float*)d_in[0];
    const float* W_ih = (const float*)d_in[1];
    const float* W_hh = (const float*)d_in[2];
    const float* b_ih = (const float*)d_in[3];
    const float* b_hh = (const float*)d_in[4];
    const float* W_fc = (const float*)d_in[5];
    const float* b_fc = (const float*)d_in[6];
    float* out = (float*)d_out;
    char* wsb = (char*)d_ws;

    const size_t hs_b = (size_t)BB * HH * sizeof(float);        // 102400
    const size_t wfrags_b = (size_t)13 * 4 * 64 * 8 * 2;        // 53248
    const size_t whh_b = (size_t)GG * 56 * sizeof(float);       // 44800
    const size_t bias_b = 1024;
    const size_t fixed_b = 2 * hs_b + wfrags_b + whh_b + bias_b;

    int Tc = TT;
    while (Tc > 64 && (size_t)BB * Tc * GG * 2 + fixed_b > ws_size)
        Tc >>= 1;

    _Float16* xp16 = (_Float16*)wsb;
    char* p = wsb + (size_t)BB * Tc * GG * 2;
    float* hsbuf = (float*)p;            p += hs_b;
    float* csbuf = (float*)p;            p += hs_b;
    _Float16* wfrags = (_Float16*)p;     p += wfrags_b;
    float* whh32 = (float*)p;            p += whh_b;
    float* biasv = (float*)p;

    prep_kernel<<<25, 256, 0, stream>>>(W_ih, W_hh, b_ih, b_hh, wfrags, whh32, biasv);

    const int nch = TT / Tc;
    for (int j = 0; j < nch; ++j) {
        xproj_mfma<<<BB, 256, 0, stream>>>(x, wfrags, biasv, xp16, j * Tc, Tc >> 6);
        lstm_rec<<<BB, 256, 0, stream>>>(xp16, whh32, hsbuf, csbuf, Tc, j == 0);
    }
    fc_kernel<<<(BB * 10 + 255) / 256, 256, 0, stream>>>(hsbuf, W_fc, b_fc, out);
}

// Round 14
// 349.132 us; speedup vs baseline: 1.3211x; 1.3211x over previous
//
#include <hip/hip_runtime.h>

// LSTM: B=512, T=512, I=128, H=50, O=10, fp32.
// R18: R17 fused kernel with the h-read STRIDE BUG fixed.
//  R17 failed (2.7e-2) because the rec h-broadcast reads used R16's f32
//  stride on an f16 buffer: (&hbuf[p][0] + j*4) = 8-byte steps -> seven
//  16B reads OVERLAPPED (h[32..49] never read, h[4..31] double-counted
//  misaligned). Fix: hbuf[p] + j*8 (f16 elements, 16B stride) — R15's
//  proven form. No other changes (one variable per round).
//  Fusion (unchanged from R17): per 64-t chunk, MFMA phase writes xp+bias
//  into LDS xbuf; rec phase consumes via ds_read_u16; next chunk's x
//  prefetched into 32 VGPRs during MFMA, consumed a chunk later (134MB of
//  x reads amortize under rec phases). xp never touches HBM; h/c live in
//  registers across all 512 steps; fc in tail; fast v_rcp in activations.

#define BB 512
#define TT 512
#define II 128
#define HH 50
#define GG 200   // 4*H

typedef _Float16 half2v __attribute__((ext_vector_type(2)));
typedef _Float16 half8v __attribute__((ext_vector_type(8)));
typedef float float4v __attribute__((ext_vector_type(4)));

#if defined(__has_builtin)
#if __has_builtin(__builtin_amdgcn_fdot2)
#define HAVE_FDOT2 1
#endif
#if __has_builtin(__builtin_amdgcn_rcpf)
#define HAVE_RCPF 1
#endif
#endif

__device__ __forceinline__ float fdot2f(half2v a, half2v b, float c) {
#ifdef HAVE_FDOT2
    return __builtin_amdgcn_fdot2(a, b, c, false);
#else
    return c + (float)a[0] * (float)b[0] + (float)a[1] * (float)b[1];
#endif
}

__device__ __forceinline__ float frcp(float x) {
#ifdef HAVE_RCPF
    return __builtin_amdgcn_rcpf(x);
#else
    return 1.f / x;
#endif
}
__device__ __forceinline__ float fsig(float x) {
    return frcp(1.f + __expf(-x));
}
__device__ __forceinline__ float ftanh(float x) {
    return 2.f * fsig(2.f * x) - 1.f;
}

// ---------------- Kernel 0: prep (once per launch) ----------------
// Gate permutation: gp = unit*4 + gate  <->  orig g = gate*50 + unit.
// wfrags: W_ih rows in PERMUTED order as f16 MFMA B-fragments
//         [nt 13][kc 4][lane 64][j 8]
// whh16:  W_hh rows padded to 56 f16, ORIGINAL order  [g 200][56]
// biasv:  b_ih + b_hh in PERMUTED order               [gp 200]
__global__ __launch_bounds__(256) void prep_kernel(
    const float* __restrict__ W_ih, const float* __restrict__ W_hh,
    const float* __restrict__ b_ih, const float* __restrict__ b_hh,
    _Float16* __restrict__ wfrags, _Float16* __restrict__ whh16,
    float* __restrict__ biasv)
{
    int idx = blockIdx.x * 256 + threadIdx.x;
    if (idx < 3328) {                       // 13*4*64 fragment slots
        int lane = idx & 63, kc = (idx >> 6) & 3, nt = idx >> 8;
        int gp = nt * 16 + (lane & 15);     // permuted gate index
        int k0 = kc * 32 + ((lane >> 4) & 3) * 8;
        half8v v;
        if (gp < GG) {
            int u = gp >> 2, j = gp & 3;
            const float* wr = W_ih + (size_t)(j * HH + u) * II + k0;
            #pragma unroll
            for (int q = 0; q < 8; ++q) v[q] = (_Float16)wr[q];
        } else {
            #pragma unroll
            for (int q = 0; q < 8; ++q) v[q] = (_Float16)0.f;
        }
        *(half8v*)(wfrags + (size_t)idx * 8) = v;
    } else if (idx < 3328 + 2800) {         // 200 rows * 14 quads
        int r = idx - 3328;
        int g = r / 14, j4 = r % 14;
        #pragma unroll
        for (int j = 0; j < 4; ++j) {
            int hidx = j4 * 4 + j;
            whh16[g * 56 + hidx] = (hidx < HH) ? (_Float16)W_hh[g * HH + hidx]
                                               : (_Float16)0.f;
        }
    } else if (idx < 3328 + 2800 + GG) {
        int gp = idx - 6128;
        int u = gp >> 2, j = gp & 3;
        biasv[gp] = b_ih[j * HH + u] + b_hh[j * HH + u];
    }
}

// ---------------- Kernel 1: fused xproj(MFMA) + recurrence + FC ------------
// Block = batch b (512 blocks, 256 thr, 2 blocks/CU at ~79KB LDS).
__global__
__attribute__((amdgpu_flat_work_group_size(256, 256)))
__attribute__((amdgpu_waves_per_eu(1, 2)))
void lstm_fused(
    const float* __restrict__ x, const _Float16* __restrict__ wfrags,
    const float* __restrict__ biasv, const _Float16* __restrict__ whh16,
    const float* __restrict__ W_fc, const float* __restrict__ b_fc,
    float* __restrict__ out)
{
    __shared__ __align__(16) _Float16 wflds[3328 * 8];   // 53248 B
    __shared__ __align__(16) _Float16 xbuf[64 * GG];     // 25600 B
    __shared__ float blds[GG];                           // 800 B
    __shared__ __align__(16) _Float16 hbuf[2][56];       // 224 B
    __shared__ float hf32[HH];                           // 200 B
    const int tid = threadIdx.x;
    const int b = blockIdx.x;
    const int w = tid >> 6, l = tid & 63;

    // ---- one-time staging: W_ih fragments + bias into LDS ----
    for (int s = tid; s < 3328; s += 256)
        *(float4v*)(wflds + (size_t)s * 8) = *(const float4v*)(wfrags + (size_t)s * 8);
    for (int s = tid; s < GG; s += 256) blds[s] = biasv[s];

    // ---- rec lane constants (gate-per-lane; pads mirror gp=197) ----
    const int gp = (tid < GG) ? tid : 197;
    const int u = gp >> 2;
    const int gate = gp & 3;
    const int wrow = gate * HH + u;          // original W_hh row order

    // Per-lane W_hh row: 7 x b128 = 28 VGPRs (f16-packed), one-time load.
    float4v wv[7];
    #pragma unroll
    for (int j = 0; j < 7; ++j)
        wv[j] = *(const float4v*)(whh16 + (size_t)wrow * 56 + j * 8);

    // ---- MFMA A-fragment source (R9/R11-verified mapping) ----
    const int row = w * 16 + (l & 15);
    const int kq = (l >> 4) & 3;
    const float* xbase = x + ((size_t)b * TT + row) * II + kq * 8;

    // Prologue: chunk 0 A-data (8 float4 = 32 VGPRs).
    float4 f0[4], f1[4];
    #pragma unroll
    for (int kc = 0; kc < 4; ++kc) {
        f0[kc] = *(const float4*)(xbase + kc * 32);
        f1[kc] = *(const float4*)(xbase + kc * 32 + 4);
    }

    // h/c init (h0 = c0 = 0); pads 50..55 of both parities stay 0 forever.
    if (tid < 56) {
        hbuf[0][tid] = (_Float16)0.f;
        hbuf[1][tid] = (_Float16)0.f;
    }
    float c = 0.f, hlast = 0.f;
    __syncthreads();   // wflds/blds/hbuf ready

    const int colb = l & 15, rq = l >> 4;

    for (int ch = 0; ch < 8; ++ch) {
        // ---------- MFMA phase: xp for t in [ch*64, ch*64+64) ----------
        half8v a[4];
        #pragma unroll
        for (int kc = 0; kc < 4; ++kc) {
            a[kc][0] = (_Float16)f0[kc].x; a[kc][1] = (_Float16)f0[kc].y;
            a[kc][2] = (_Float16)f0[kc].z; a[kc][3] = (_Float16)f0[kc].w;
            a[kc][4] = (_Float16)f1[kc].x; a[kc][5] = (_Float16)f1[kc].y;
            a[kc][6] = (_Float16)f1[kc].z; a[kc][7] = (_Float16)f1[kc].w;
        }
        // Prefetch next chunk's x into regs; consumed ~28us later (fully
        // hidden under this chunk's rec phase).
        if (ch + 1 < 8) {
            const float* xn = xbase + (size_t)(ch + 1) * 64 * II;
            #pragma unroll
            for (int kc = 0; kc < 4; ++kc) {
                f0[kc] = *(const float4*)(xn + kc * 32);
                f1[kc] = *(const float4*)(xn + kc * 32 + 4);
            }
        }

        float4v acc[13];
        #pragma unroll
        for (int nt = 0; nt < 13; ++nt) acc[nt] = (float4v){0.f, 0.f, 0.f, 0.f};
        #pragma unroll
        for (int kc = 0; kc < 4; ++kc) {
            #pragma unroll
            for (int nt = 0; nt < 13; ++nt) {
                half8v bf = *(const half8v*)(wflds + (size_t)(((nt * 4 + kc) * 64) + l) * 8);
                acc[nt] = __builtin_amdgcn_mfma_f32_16x16x32_f16(a[kc], bf, acc[nt], 0, 0, 0);
            }
        }
        // Write xp+bias into xbuf. Safe: prev rec phase's last barrier
        // ordered all xbuf reads before this point.
        #pragma unroll
        for (int nt = 0; nt < 13; ++nt) {
            int g = nt * 16 + colb;
            if (g < GG) {
                float bs = blds[g];
                #pragma unroll
                for (int reg = 0; reg < 4; ++reg)
                    xbuf[(w * 16 + rq * 4 + reg) * GG + g] = (_Float16)(acc[nt][reg] + bs);
            }
        }
        __syncthreads();   // xbuf ready for all waves

        // ---------- REC phase: 64 steps from LDS ----------
        #pragma unroll 4
        for (int t = 0; t < 64; ++t) {
            const int p = t & 1;     // static after unroll; 64 even -> parity
                                     // continuous across chunks
            // h broadcast: 7 b128 uniform-address reads.
            // FIX (R17 bug): stride is 8 f16 = 16B, not 4.
            float4v hv[7];
            #pragma unroll
            for (int j = 0; j < 7; ++j)
                hv[j] = *(const float4v*)(hbuf[p] + j * 8);

            float xpf = (float)xbuf[t * GG + gp];   // ds_read_u16, imm offset

            // 28 fdot2 (real v_dot2), 4-way split accumulators.
            float a0 = 0.f, a1 = 0.f, a2 = 0.f, a3 = 0.f;
            #pragma unroll
            for (int j = 0; j < 7; ++j) {
                const half2v* hp = (const half2v*)&hv[j];
                const half2v* wp = (const half2v*)&wv[j];
                a0 = fdot2f(hp[0], wp[0], a0);
                a1 = fdot2f(hp[1], wp[1], a1);
                a2 = fdot2f(hp[2], wp[2], a2);
                a3 = fdot2f(hp[3], wp[3], a3);
            }
            float acg = ((a0 + a1) + (a2 + a3)) + xpf;

            // sigmoid for i,f,o; tanh for g — branchless, fast rcp.
            bool isg = (gate == 2);
            float xin = isg ? 2.f * acg : acg;
            float sg = fsig(xin);
            float act = isg ? (2.f * sg - 1.f) : sg;

            // Quad broadcast: lanes u*4..u*4+3 hold (i,f,g,o) of unit u.
            int ai = __builtin_bit_cast(int, act);
            float gi = __builtin_bit_cast(float, __builtin_amdgcn_mov_dpp(ai, 0x00, 0xF, 0xF, true));
            float gf = __builtin_bit_cast(float, __builtin_amdgcn_mov_dpp(ai, 0x55, 0xF, 0xF, true));
            float gg = __builtin_bit_cast(float, __builtin_amdgcn_mov_dpp(ai, 0xAA, 0xF, 0xF, true));
            float go = __builtin_bit_cast(float, __builtin_amdgcn_mov_dpp(ai, 0xFF, 0xF, 0xF, true));

            c = gf * c + gi * gg;            // quad-redundant, consistent
            float hn = go * ftanh(c);

            // Leader writes NEXT parity buffer; dbuf => one barrier/step is
            // provably race-free (R15/R16 proven).
            if (tid < GG && gate == 0) hbuf[p ^ 1][u] = (_Float16)hn;
            __syncthreads();

            hlast = hn;
        }
    }

    // ---------- FC tail: out[b][0..9] from f32 h_last ----------
    if (tid < GG && gate == 0) hf32[u] = hlast;
    __syncthreads();
    if (tid < 10) {
        float a = b_fc[tid];
        #pragma unroll
        for (int kx = 0; kx < HH; ++kx)
            a += hf32[kx] * W_fc[tid * HH + kx];
        out[b * 10 + tid] = a;
    }
}

extern "C" void kernel_launch(void* const* d_in, const int* in_sizes, int n_in,
                              void* d_out, int out_size, void* d_ws, size_t ws_size,
                              hipStream_t stream)
{
    const float* x    = (const float*)d_in[0];
    const float* W_ih = (const float*)d_in[1];
    const float* W_hh = (const float*)d_in[2];
    const float* b_ih = (const float*)d_in[3];
    const float* b_hh = (const float*)d_in[4];
    const float* W_fc = (const float*)d_in[5];
    const float* b_fc = (const float*)d_in[6];
    float* out = (float*)d_out;
    char* wsb = (char*)d_ws;

    _Float16* wfrags = (_Float16*)wsb;                      // 53248 B
    _Float16* whh16  = (_Float16*)(wsb + 53248);            // 22400 B
    float*    biasv  = (float*)(wsb + 53248 + 22400);       // 800 B

    prep_kernel<<<25, 256, 0, stream>>>(W_ih, W_hh, b_ih, b_hh,
                                        wfrags, whh16, biasv);
    lstm_fused<<<BB, 256, 0, stream>>>(x, wfrags, biasv, whh16,
                                       W_fc, b_fc, out);
}